// Round 7
// baseline (340.221 us; speedup 1.0000x reference)
//
#include <hip/hip_runtime.h>

#define NN 100000
#define NE 1600000
#define NBKT 196                 // ceil(NN / 512)
#define EPB 8192                 // edges per block in binning passes
#define ABLK ((NE + EPB - 1) / EPB)  // 196
typedef unsigned short u16;
typedef unsigned int u32;

// ---- bf16 helpers (round-to-nearest-even) ----
__device__ __forceinline__ u32 f2bf(float f) {
    u32 u = __float_as_uint(f);
    return (u + 0x7fffu + ((u >> 16) & 1u)) >> 16;
}
__device__ __forceinline__ u32 pack2(float a, float b) {
    return f2bf(a) | (f2bf(b) << 16);
}

// ---------------- pass A1: per-bucket edge counts (bucket = dst >> 9) -------
__global__ __launch_bounds__(256) void kA1_count(const int* __restrict__ dst,
                                                 int* __restrict__ gcnt) {
    __shared__ int bc[NBKT];
    const int tid = threadIdx.x;
    for (int i = tid; i < NBKT; i += 256) bc[i] = 0;
    __syncthreads();
    const int e0 = blockIdx.x * EPB;
#pragma unroll
    for (int i = 0; i < EPB / 256; ++i) {
        const int e = e0 + i * 256 + tid;
        if (e < NE) atomicAdd(&bc[dst[e] >> 9], 1);
    }
    __syncthreads();
    for (int i = tid; i < NBKT; i += 256)
        if (bc[i]) atomicAdd(&gcnt[i], bc[i]);
}

// ---------------- pass A2: exclusive scan of 196 bucket counts --------------
__global__ __launch_bounds__(256) void kA2_scan(const int* __restrict__ gcnt,
                                                int* __restrict__ bbase,
                                                int* __restrict__ bfill,
                                                int* __restrict__ off) {
    const int t = threadIdx.x;
    const int lane = t & 63, w = t >> 6;
    const int v = (t < NBKT) ? gcnt[t] : 0;
    int s = v;
#pragma unroll
    for (int o = 1; o < 64; o <<= 1) {
        const int u = __shfl_up(s, o);
        if (lane >= o) s += u;
    }
    __shared__ int ws[4];
    if (lane == 63) ws[w] = s;
    __syncthreads();
    int add = 0;
    for (int i = 0; i < w; ++i) add += ws[i];
    const int excl = s + add - v;
    if (t < NBKT) { bbase[t] = excl; bfill[t] = excl; }
    if (t == NBKT) bbase[NBKT] = NE;
    if (t == 255) off[NN] = NE;
}

// ---------------- pass A3: bin edges (packed src<<9 | dst&511) --------------
__global__ __launch_bounds__(256) void kA3_bin(const int* __restrict__ src,
                                               const int* __restrict__ dst,
                                               int* __restrict__ bfill,
                                               u32* __restrict__ binned) {
    __shared__ int bc[NBKT];
    __shared__ int cbase[NBKT];
    const int tid = threadIdx.x;
    for (int i = tid; i < NBKT; i += 256) bc[i] = 0;
    __syncthreads();
    const int e0 = blockIdx.x * EPB;
#pragma unroll
    for (int i = 0; i < EPB / 256; ++i) {
        const int e = e0 + i * 256 + tid;
        if (e < NE) atomicAdd(&bc[dst[e] >> 9], 1);
    }
    __syncthreads();
    for (int i = tid; i < NBKT; i += 256)
        cbase[i] = bc[i] ? atomicAdd(&bfill[i], bc[i]) : 0;
    __syncthreads();
    for (int i = tid; i < NBKT; i += 256) bc[i] = 0;  // reuse as cursor
    __syncthreads();
#pragma unroll
    for (int i = 0; i < EPB / 256; ++i) {
        const int e = e0 + i * 256 + tid;
        if (e < NE) {
            const int d = dst[e];
            const int bkt = d >> 9;
            const int p = atomicAdd(&bc[bkt], 1);
            binned[cbase[bkt] + p] = ((u32)src[e] << 9) | (u32)(d & 511);
        }
    }
}

// ---------------- pass B: per-bucket count+scan -> off/dinv, fill csr.x -----
__global__ __launch_bounds__(256) void kB_fill(const u32* __restrict__ binned,
                                               const int* __restrict__ bbase,
                                               int* __restrict__ off,
                                               float* __restrict__ dinv,
                                               uint2* __restrict__ csr) {
    __shared__ int lcnt[512];
    __shared__ int lpos[512];
    __shared__ int ws[4];
    const int b = blockIdx.x;
    const int tid = threadIdx.x;
    const int e0 = bbase[b], e1 = bbase[b + 1];
    const int node0 = b << 9;
    lcnt[tid] = 0;
    lcnt[tid + 256] = 0;
    __syncthreads();
    for (int e = e0 + tid; e < e1; e += 256)
        atomicAdd(&lcnt[binned[e] & 511], 1);
    __syncthreads();
    const int c0 = lcnt[tid * 2], c1 = lcnt[tid * 2 + 1];
    const int s = c0 + c1;
    const int lane = tid & 63, w = tid >> 6;
    int incl = s;
#pragma unroll
    for (int o = 1; o < 64; o <<= 1) {
        const int u = __shfl_up(incl, o);
        if (lane >= o) incl += u;
    }
    if (lane == 63) ws[w] = incl;
    __syncthreads();
    int base = incl - s;
    for (int i = 0; i < w; ++i) base += ws[i];
    lpos[tid * 2] = base;
    lpos[tid * 2 + 1] = base + c0;
    const int n0 = node0 + tid * 2;
    if (n0 < NN)     { off[n0] = e0 + base;          dinv[n0] = rsqrtf(1.0f + (float)c0); }
    if (n0 + 1 < NN) { off[n0 + 1] = e0 + base + c0; dinv[n0 + 1] = rsqrtf(1.0f + (float)c1); }
    __syncthreads();
    for (int e = e0 + tid; e < e1; e += 256) {
        const u32 u = binned[e];
        const int p = atomicAdd(&lpos[u & 511], 1);
        csr[e0 + p] = make_uint2(u >> 9, 0u);
    }
}

// ---------------- fill per-edge weight: csr[i].y = dinv[csr[i].x] -----------
__global__ __launch_bounds__(256) void k_wgt(uint2* __restrict__ csr,
                                             const float* __restrict__ dinv) {
    const int i = blockIdx.x * 256 + threadIdx.x;
    if (i < NE) {
        uint2 c = csr[i];
        c.y = __float_as_uint(dinv[c.x]);
        csr[i] = c;
    }
}

// ---------------- tiled GEMM: out[NNx128](bf16) = in[NNxK] @ W[Kx128] -------
template<int K, bool BF16IN>
__global__ __launch_bounds__(256) void k_gemm(const void* __restrict__ inp,
                                              const float* __restrict__ W,
                                              u16* __restrict__ out) {
    __shared__ float sW[K * 128];
    __shared__ float sX[32 * K];
    const int tid = threadIdx.x;
    const long long row0 = (long long)blockIdx.x * 32;

#pragma unroll
    for (int t = 0; t < K * 128 / 1024; ++t) {
        const int idx = (t * 256 + tid) * 4;
        *reinterpret_cast<float4*>(&sW[idx]) =
            *reinterpret_cast<const float4*>(&W[idx]);
    }
    if constexpr (BF16IN) {
        const u16* inb = (const u16*)inp;
#pragma unroll
        for (int t = 0; t < 32 * K / 2048; ++t) {
            const int idx = (t * 256 + tid) * 8;
            uint4 v = *reinterpret_cast<const uint4*>(&inb[row0 * K + idx]);
            sX[idx + 0] = __uint_as_float(v.x << 16);
            sX[idx + 1] = __uint_as_float(v.x & 0xffff0000u);
            sX[idx + 2] = __uint_as_float(v.y << 16);
            sX[idx + 3] = __uint_as_float(v.y & 0xffff0000u);
            sX[idx + 4] = __uint_as_float(v.z << 16);
            sX[idx + 5] = __uint_as_float(v.z & 0xffff0000u);
            sX[idx + 6] = __uint_as_float(v.w << 16);
            sX[idx + 7] = __uint_as_float(v.w & 0xffff0000u);
        }
    } else {
        const float* inf = (const float*)inp;
#pragma unroll
        for (int t = 0; t < 32 * K / 1024; ++t) {
            const int idx = (t * 256 + tid) * 4;
            *reinterpret_cast<float4*>(&sX[idx]) =
                *reinterpret_cast<const float4*>(&inf[row0 * K + idx]);
        }
    }
    __syncthreads();

    const int jc = (tid & 31) * 4;
    const int ir = (tid >> 5) * 4;
    float acc[4][4] = {};

#pragma unroll
    for (int k = 0; k < K; k += 2) {
        const float4 w0 = *reinterpret_cast<const float4*>(&sW[k * 128 + jc]);
        const float4 w1 = *reinterpret_cast<const float4*>(&sW[(k + 1) * 128 + jc]);
#pragma unroll
        for (int r = 0; r < 4; ++r) {
            const float2 xv = *reinterpret_cast<const float2*>(&sX[(ir + r) * K + k]);
            acc[r][0] += xv.x * w0.x + xv.y * w1.x;
            acc[r][1] += xv.x * w0.y + xv.y * w1.y;
            acc[r][2] += xv.x * w0.z + xv.y * w1.z;
            acc[r][3] += xv.x * w0.w + xv.y * w1.w;
        }
    }

#pragma unroll
    for (int r = 0; r < 4; ++r) {
        uint2 o;
        o.x = pack2(acc[r][0], acc[r][1]);
        o.y = pack2(acc[r][2], acc[r][3]);
        *reinterpret_cast<uint2*>(&out[(row0 + ir + r) * 128 + jc]) = o;
    }
}

// ---------------- fused: CSR gather-sum(bf16) + bias + LayerNorm + ReLU -----
// one wave per node; sub = lane>>4 owns one of 4 edges in flight,
// l = lane&15 owns 8 cols (16 B) of the row.
template<bool FP32OUT>
__global__ __launch_bounds__(256) void k_agg_ln(const u16* __restrict__ A,
                                                const int* __restrict__ off,
                                                const uint2* __restrict__ csr,
                                                const float* __restrict__ dinv,
                                                const float* __restrict__ b,
                                                const float* __restrict__ g,
                                                const float* __restrict__ bt,
                                                void* __restrict__ outp) {
    const int node = blockIdx.x * 4 + (threadIdx.x >> 6);
    const int lane = threadIdx.x & 63;
    const int sub = lane >> 4;
    const int l = lane & 15;
    const char* Ab = (const char*)A;
    const u32 coff = (u32)l << 4;

    const float di = dinv[node];
    float a[8] = {};

    // self loop (only sub 0 accumulates; all lanes share the cached row)
    {
        const uint4 u = *(const uint4*)(Ab + ((u32)node << 8) + coff);
        const float w = (sub == 0) ? di * di : 0.0f;
        a[0] += __uint_as_float(u.x << 16) * w;
        a[1] += __uint_as_float(u.x & 0xffff0000u) * w;
        a[2] += __uint_as_float(u.y << 16) * w;
        a[3] += __uint_as_float(u.y & 0xffff0000u) * w;
        a[4] += __uint_as_float(u.z << 16) * w;
        a[5] += __uint_as_float(u.z & 0xffff0000u) * w;
        a[6] += __uint_as_float(u.w << 16) * w;
        a[7] += __uint_as_float(u.w & 0xffff0000u) * w;
    }

    const int e0 = off[node], e1 = off[node + 1];
    for (int base = e0; base < e1; base += 4) {
        const int e = base + sub;
        const int ee = min(e, e1 - 1);
        const uint2 cw = csr[ee];
        const float w = (e < e1) ? __uint_as_float(cw.y) * di : 0.0f;
        const uint4 u = *(const uint4*)(Ab + (cw.x << 8) + coff);
        a[0] += __uint_as_float(u.x << 16) * w;
        a[1] += __uint_as_float(u.x & 0xffff0000u) * w;
        a[2] += __uint_as_float(u.y << 16) * w;
        a[3] += __uint_as_float(u.y & 0xffff0000u) * w;
        a[4] += __uint_as_float(u.z << 16) * w;
        a[5] += __uint_as_float(u.z & 0xffff0000u) * w;
        a[6] += __uint_as_float(u.w << 16) * w;
        a[7] += __uint_as_float(u.w & 0xffff0000u) * w;
    }

    // reduce across the 4 edge sub-groups (lanes l, l+16, l+32, l+48)
#pragma unroll
    for (int i = 0; i < 8; ++i) {
        a[i] += __shfl_xor(a[i], 16);
        a[i] += __shfl_xor(a[i], 32);
    }

    // bias (once, after sub-reduce)
    const int c = l * 8;
    {
        const float4 b0 = *(const float4*)&b[c];
        const float4 b1 = *(const float4*)&b[c + 4];
        a[0] += b0.x; a[1] += b0.y; a[2] += b0.z; a[3] += b0.w;
        a[4] += b1.x; a[5] += b1.y; a[6] += b1.z; a[7] += b1.w;
    }

    // LayerNorm stats over 128 cols (16 lanes x 8 each; subs are identical)
    float s1 = 0.f, s2 = 0.f;
#pragma unroll
    for (int i = 0; i < 8; ++i) { s1 += a[i]; s2 += a[i] * a[i]; }
#pragma unroll
    for (int o = 1; o < 16; o <<= 1) {
        s1 += __shfl_xor(s1, o);
        s2 += __shfl_xor(s2, o);
    }
    const float mu = s1 * (1.0f / 128.0f);
    const float var = s2 * (1.0f / 128.0f) - mu * mu;
    const float r = rsqrtf(var + 1e-5f);

    if (sub == 0) {
        const float4 g0 = *(const float4*)&g[c];
        const float4 g1 = *(const float4*)&g[c + 4];
        const float4 t0 = *(const float4*)&bt[c];
        const float4 t1 = *(const float4*)&bt[c + 4];
        float y[8];
        y[0] = fmaxf((a[0] - mu) * r * g0.x + t0.x, 0.f);
        y[1] = fmaxf((a[1] - mu) * r * g0.y + t0.y, 0.f);
        y[2] = fmaxf((a[2] - mu) * r * g0.z + t0.z, 0.f);
        y[3] = fmaxf((a[3] - mu) * r * g0.w + t0.w, 0.f);
        y[4] = fmaxf((a[4] - mu) * r * g1.x + t1.x, 0.f);
        y[5] = fmaxf((a[5] - mu) * r * g1.y + t1.y, 0.f);
        y[6] = fmaxf((a[6] - mu) * r * g1.z + t1.z, 0.f);
        y[7] = fmaxf((a[7] - mu) * r * g1.w + t1.w, 0.f);
        if constexpr (FP32OUT) {
            float* orow = (float*)outp + (size_t)node * 128 + c;
            float4 o0; o0.x = y[0]; o0.y = y[1]; o0.z = y[2]; o0.w = y[3];
            float4 o1; o1.x = y[4]; o1.y = y[5]; o1.z = y[6]; o1.w = y[7];
            *(float4*)(orow) = o0;
            *(float4*)(orow + 4) = o1;
        } else {
            uint4 o;
            o.x = pack2(y[0], y[1]);
            o.y = pack2(y[2], y[3]);
            o.z = pack2(y[4], y[5]);
            o.w = pack2(y[6], y[7]);
            *(uint4*)((char*)outp + ((u32)node << 8) + coff) = o;
        }
    }
}

extern "C" void kernel_launch(void* const* d_in, const int* in_sizes, int n_in,
                              void* d_out, int out_size, void* d_ws, size_t ws_size,
                              hipStream_t stream) {
    const float* x   = (const float*)d_in[0];
    const int*   ei  = (const int*)d_in[1];
    const float* W1  = (const float*)d_in[2];
    const float* b1  = (const float*)d_in[3];
    const float* g1  = (const float*)d_in[4];
    const float* bt1 = (const float*)d_in[5];
    const float* W2  = (const float*)d_in[6];
    const float* b2  = (const float*)d_in[7];
    const float* g2  = (const float*)d_in[8];
    const float* bt2 = (const float*)d_in[9];

    const int* src = ei;
    const int* dst = ei + NE;
    float* out = (float*)d_out;

    // workspace layout (4B units)
    const int NP = (NN + 256 + 255) & ~255;  // covers NN+1
    int*   gcnt    = (int*)d_ws;              // 256
    int*   bbase   = gcnt + 256;              // 256 (197 used)
    int*   bfill   = bbase + 256;             // 256
    int*   off     = bfill + 256;             // NP
    float* dinv    = (float*)(off + NP);      // NP
    uint2* csr     = (uint2*)(dinv + NP);     // NE uint2 {src, dinv[src]} (12.8 MB)
    u16*   A       = (u16*)(csr + NE);        // NN*128 bf16 (25.6 MB)
    u32*   binned  = (u32*)A;                 // NE u32, aliases A (dead before gemm1)
    u16*   h1      = (u16*)d_out;             // NN*128 bf16 in d_out (dead before final write)

    // ---- build CSR via two-level binned counting sort ----
    hipMemsetAsync(gcnt, 0, NBKT * sizeof(int), stream);
    kA1_count<<<ABLK, 256, 0, stream>>>(dst, gcnt);
    kA2_scan<<<1, 256, 0, stream>>>(gcnt, bbase, bfill, off);
    kA3_bin<<<ABLK, 256, 0, stream>>>(src, dst, bfill, binned);
    kB_fill<<<NBKT, 256, 0, stream>>>(binned, bbase, off, dinv, csr);
    k_wgt<<<(NE + 255) / 256, 256, 0, stream>>>(csr, dinv);

    // ---- layer 1 ----
    k_gemm<64, false><<<NN / 32, 256, 0, stream>>>(x, W1, A);
    k_agg_ln<false><<<NN / 4, 256, 0, stream>>>(A, off, csr, dinv,
                                                b1, g1, bt1, h1);

    // ---- layer 2 ----
    k_gemm<128, true><<<NN / 32, 256, 0, stream>>>(h1, W2, A);
    k_agg_ln<true><<<NN / 4, 256, 0, stream>>>(A, off, csr, dinv,
                                               b2, g2, bt2, out);
}

// Round 8
// 252.955 us; speedup vs baseline: 1.3450x; 1.3450x over previous
//
#include <hip/hip_runtime.h>

#define NN 100000
#define NE 1600000
#define NBKT 196                 // ceil(NN / 512)
#define EPB 8192                 // edges per block in binning passes
#define ABLK ((NE + EPB - 1) / EPB)  // 196
typedef unsigned short u16;
typedef unsigned int u32;

typedef __attribute__((ext_vector_type(8))) short short8v;
typedef __attribute__((ext_vector_type(4))) float f32x4;

// ---- bf16 helpers (round-to-nearest-even) ----
__device__ __forceinline__ u32 f2bf(float f) {
    u32 u = __float_as_uint(f);
    return (u + 0x7fffu + ((u >> 16) & 1u)) >> 16;
}
__device__ __forceinline__ u32 pack2(float a, float b) {
    return f2bf(a) | (f2bf(b) << 16);
}
__device__ __forceinline__ void accum8(float* a, uint4 u, float w) {
    a[0] += __uint_as_float(u.x << 16) * w;
    a[1] += __uint_as_float(u.x & 0xffff0000u) * w;
    a[2] += __uint_as_float(u.y << 16) * w;
    a[3] += __uint_as_float(u.y & 0xffff0000u) * w;
    a[4] += __uint_as_float(u.z << 16) * w;
    a[5] += __uint_as_float(u.z & 0xffff0000u) * w;
    a[6] += __uint_as_float(u.w << 16) * w;
    a[7] += __uint_as_float(u.w & 0xffff0000u) * w;
}

// ---------------- pass A1: per-bucket edge counts (bucket = dst >> 9) -------
__global__ __launch_bounds__(256) void kA1_count(const int* __restrict__ dst,
                                                 int* __restrict__ gcnt) {
    __shared__ int bc[NBKT];
    const int tid = threadIdx.x;
    for (int i = tid; i < NBKT; i += 256) bc[i] = 0;
    __syncthreads();
    const int e0 = blockIdx.x * EPB;
#pragma unroll
    for (int i = 0; i < EPB / 256; ++i) {
        const int e = e0 + i * 256 + tid;
        if (e < NE) atomicAdd(&bc[dst[e] >> 9], 1);
    }
    __syncthreads();
    for (int i = tid; i < NBKT; i += 256)
        if (bc[i]) atomicAdd(&gcnt[i], bc[i]);
}

// ---------------- pass A2: exclusive scan of 196 bucket counts --------------
__global__ __launch_bounds__(256) void kA2_scan(const int* __restrict__ gcnt,
                                                int* __restrict__ bbase,
                                                int* __restrict__ bfill,
                                                int* __restrict__ off) {
    const int t = threadIdx.x;
    const int lane = t & 63, w = t >> 6;
    const int v = (t < NBKT) ? gcnt[t] : 0;
    int s = v;
#pragma unroll
    for (int o = 1; o < 64; o <<= 1) {
        const int u = __shfl_up(s, o);
        if (lane >= o) s += u;
    }
    __shared__ int ws[4];
    if (lane == 63) ws[w] = s;
    __syncthreads();
    int add = 0;
    for (int i = 0; i < w; ++i) add += ws[i];
    const int excl = s + add - v;
    if (t < NBKT) { bbase[t] = excl; bfill[t] = excl; }
    if (t == NBKT) bbase[NBKT] = NE;
    if (t == 255) off[NN] = NE;
}

// ---------------- pass A3: bin edges (packed src<<9 | dst&511) --------------
__global__ __launch_bounds__(256) void kA3_bin(const int* __restrict__ src,
                                               const int* __restrict__ dst,
                                               int* __restrict__ bfill,
                                               u32* __restrict__ binned) {
    __shared__ int bc[NBKT];
    __shared__ int cbase[NBKT];
    const int tid = threadIdx.x;
    for (int i = tid; i < NBKT; i += 256) bc[i] = 0;
    __syncthreads();
    const int e0 = blockIdx.x * EPB;
#pragma unroll
    for (int i = 0; i < EPB / 256; ++i) {
        const int e = e0 + i * 256 + tid;
        if (e < NE) atomicAdd(&bc[dst[e] >> 9], 1);
    }
    __syncthreads();
    for (int i = tid; i < NBKT; i += 256)
        cbase[i] = bc[i] ? atomicAdd(&bfill[i], bc[i]) : 0;
    __syncthreads();
    for (int i = tid; i < NBKT; i += 256) bc[i] = 0;  // reuse as cursor
    __syncthreads();
#pragma unroll
    for (int i = 0; i < EPB / 256; ++i) {
        const int e = e0 + i * 256 + tid;
        if (e < NE) {
            const int d = dst[e];
            const int bkt = d >> 9;
            const int p = atomicAdd(&bc[bkt], 1);
            binned[cbase[bkt] + p] = ((u32)src[e] << 9) | (u32)(d & 511);
        }
    }
}

// ---------------- pass B: per-bucket count+scan -> off/dinv, fill csr_tmp ---
__global__ __launch_bounds__(256) void kB_fill(const u32* __restrict__ binned,
                                               const int* __restrict__ bbase,
                                               int* __restrict__ off,
                                               float* __restrict__ dinv,
                                               int* __restrict__ csr_tmp) {
    __shared__ int lcnt[512];
    __shared__ int lpos[512];
    __shared__ int ws[4];
    const int b = blockIdx.x;
    const int tid = threadIdx.x;
    const int e0 = bbase[b], e1 = bbase[b + 1];
    const int node0 = b << 9;
    lcnt[tid] = 0;
    lcnt[tid + 256] = 0;
    __syncthreads();
    for (int e = e0 + tid; e < e1; e += 256)
        atomicAdd(&lcnt[binned[e] & 511], 1);
    __syncthreads();
    const int c0 = lcnt[tid * 2], c1 = lcnt[tid * 2 + 1];
    const int s = c0 + c1;
    const int lane = tid & 63, w = tid >> 6;
    int incl = s;
#pragma unroll
    for (int o = 1; o < 64; o <<= 1) {
        const int u = __shfl_up(incl, o);
        if (lane >= o) incl += u;
    }
    if (lane == 63) ws[w] = incl;
    __syncthreads();
    int base = incl - s;
    for (int i = 0; i < w; ++i) base += ws[i];
    lpos[tid * 2] = base;
    lpos[tid * 2 + 1] = base + c0;
    const int n0 = node0 + tid * 2;
    if (n0 < NN)     { off[n0] = e0 + base;          dinv[n0] = rsqrtf(1.0f + (float)c0); }
    if (n0 + 1 < NN) { off[n0 + 1] = e0 + base + c0; dinv[n0 + 1] = rsqrtf(1.0f + (float)c1); }
    __syncthreads();
    for (int e = e0 + tid; e < e1; e += 256) {
        const u32 u = binned[e];
        const int p = atomicAdd(&lpos[u & 511], 1);
        csr_tmp[e0 + p] = (int)(u >> 9);
    }
}

// ---------------- csr = {src, dinv[src]} ----------------
__global__ __launch_bounds__(256) void k_wgt(const int* __restrict__ csr_tmp,
                                             const float* __restrict__ dinv,
                                             uint2* __restrict__ csr) {
    const int i = blockIdx.x * 256 + threadIdx.x;
    if (i < NE) {
        const int s = csr_tmp[i];
        csr[i] = make_uint2((u32)s, __float_as_uint(dinv[s]));
    }
}

// ---------------- x fp32 -> bf16 ----------------
__global__ __launch_bounds__(256) void k_cvt(const float* __restrict__ x,
                                             u16* __restrict__ xb) {
    const int i = blockIdx.x * 256 + threadIdx.x;  // over NN*8
    if (i < NN * 8) {
        const float4 v0 = *(const float4*)&x[(size_t)i * 8];
        const float4 v1 = *(const float4*)&x[(size_t)i * 8 + 4];
        uint4 o;
        o.x = pack2(v0.x, v0.y); o.y = pack2(v0.z, v0.w);
        o.z = pack2(v1.x, v1.y); o.w = pack2(v1.z, v1.w);
        *(uint4*)&xb[(size_t)i * 8] = o;
    }
}

// ---------------- W[K][128] fp32 -> WT[128][K] bf16 (transposed) ------------
__global__ __launch_bounds__(256) void k_wt(const float* __restrict__ W,
                                            u16* __restrict__ WT, int K) {
    const int i = blockIdx.x * 256 + threadIdx.x;
    if (i < K * 128) {
        const int k = i >> 7, c = i & 127;
        WT[c * K + k] = (u16)f2bf(W[i]);
    }
}

// ---------------- gather-sum over 64 bf16 cols (8 edges in flight) ----------
__global__ __launch_bounds__(256) void k_agg64(const u16* __restrict__ A,
                                               const int* __restrict__ off,
                                               const uint2* __restrict__ csr,
                                               const float* __restrict__ dinv,
                                               u16* __restrict__ out) {
    const int node = blockIdx.x * 4 + (threadIdx.x >> 6);
    const int lane = threadIdx.x & 63;
    const int sub = lane >> 3, l = lane & 7;
    const u32 coff = (u32)l << 4;
    const char* Ab = (const char*)A;
    const float di = dinv[node];
    float a[8] = {};
    {
        const uint4 u = *(const uint4*)(Ab + (u32)node * 128u + coff);
        accum8(a, u, (sub == 0) ? di * di : 0.0f);
    }
    const int e0 = off[node], e1 = off[node + 1];
    for (int base = e0; base < e1; base += 8) {
        const int e = base + sub;
        const uint2 cw = csr[min(e, e1 - 1)];
        const float w = (e < e1) ? __uint_as_float(cw.y) * di : 0.0f;
        const uint4 u = *(const uint4*)(Ab + cw.x * 128u + coff);
        accum8(a, u, w);
    }
#pragma unroll
    for (int i = 0; i < 8; ++i) {
        a[i] += __shfl_xor(a[i], 8);
        a[i] += __shfl_xor(a[i], 16);
        a[i] += __shfl_xor(a[i], 32);
    }
    if (sub == 0) {
        uint4 o;
        o.x = pack2(a[0], a[1]); o.y = pack2(a[2], a[3]);
        o.z = pack2(a[4], a[5]); o.w = pack2(a[6], a[7]);
        *(uint4*)((char*)out + (u32)node * 128u + coff) = o;
    }
}

// ---------------- gather-sum over 128 bf16 cols (4 edges in flight) ---------
__global__ __launch_bounds__(256) void k_agg128(const u16* __restrict__ A,
                                                const int* __restrict__ off,
                                                const uint2* __restrict__ csr,
                                                const float* __restrict__ dinv,
                                                u16* __restrict__ out) {
    const int node = blockIdx.x * 4 + (threadIdx.x >> 6);
    const int lane = threadIdx.x & 63;
    const int sub = lane >> 4, l = lane & 15;
    const u32 coff = (u32)l << 4;
    const char* Ab = (const char*)A;
    const float di = dinv[node];
    float a[8] = {};
    {
        const uint4 u = *(const uint4*)(Ab + ((u32)node << 8) + coff);
        accum8(a, u, (sub == 0) ? di * di : 0.0f);
    }
    const int e0 = off[node], e1 = off[node + 1];
    for (int base = e0; base < e1; base += 4) {
        const int e = base + sub;
        const uint2 cw = csr[min(e, e1 - 1)];
        const float w = (e < e1) ? __uint_as_float(cw.y) * di : 0.0f;
        const uint4 u = *(const uint4*)(Ab + (cw.x << 8) + coff);
        accum8(a, u, w);
    }
#pragma unroll
    for (int i = 0; i < 8; ++i) {
        a[i] += __shfl_xor(a[i], 16);
        a[i] += __shfl_xor(a[i], 32);
    }
    if (sub == 0) {
        uint4 o;
        o.x = pack2(a[0], a[1]); o.y = pack2(a[2], a[3]);
        o.z = pack2(a[4], a[5]); o.w = pack2(a[6], a[7]);
        *(uint4*)((char*)out + ((u32)node << 8) + coff) = o;
    }
}

// ---------------- MFMA GEMM + bias + LayerNorm + ReLU -----------------------
// A[NN][K] bf16 @ WT[128][K] bf16 -> out [NN][128] (bf16 or fp32).
// Block 256 thr = 4 waves; wave computes 32 rows x 128 cols (2 row-tiles).
// mfma_f32_16x16x32_bf16: A row=lane&15, k=(lane>>4)*8+j; B col=lane&15 same k;
// C/D col=lane&15, row=(lane>>4)*4+reg.
template<int K, bool FP32OUT>
__global__ __launch_bounds__(256) void k_gemm_ln(const u16* __restrict__ Ain,
                                                 const u16* __restrict__ WT,
                                                 const float* __restrict__ bias,
                                                 const float* __restrict__ g,
                                                 const float* __restrict__ bt,
                                                 void* __restrict__ outp) {
    const int tid = threadIdx.x;
    const int wv = tid >> 6, lane = tid & 63;
    const int lr = lane & 15, kg = lane >> 4;
    const int row0 = blockIdx.x * 128 + wv * 32;

    short8v af[2][K / 32];
#pragma unroll
    for (int rt = 0; rt < 2; ++rt) {
        const int r = min(row0 + rt * 16 + lr, NN - 1);
#pragma unroll
        for (int kk = 0; kk < K / 32; ++kk)
            af[rt][kk] = *(const short8v*)&Ain[(size_t)r * K + kk * 32 + kg * 8];
    }
    f32x4 acc[2][8];
#pragma unroll
    for (int rt = 0; rt < 2; ++rt)
#pragma unroll
        for (int nt = 0; nt < 8; ++nt)
            acc[rt][nt] = (f32x4){0.f, 0.f, 0.f, 0.f};

#pragma unroll
    for (int nt = 0; nt < 8; ++nt) {
        const int col = nt * 16 + lr;
        short8v bf[K / 32];
#pragma unroll
        for (int kk = 0; kk < K / 32; ++kk)
            bf[kk] = *(const short8v*)&WT[col * K + kk * 32 + kg * 8];
#pragma unroll
        for (int rt = 0; rt < 2; ++rt)
#pragma unroll
            for (int kk = 0; kk < K / 32; ++kk)
                acc[rt][nt] = __builtin_amdgcn_mfma_f32_16x16x32_bf16(
                    af[rt][kk], bf[kk], acc[rt][nt], 0, 0, 0);
    }

    float bv[8], gv[8], tv[8];
#pragma unroll
    for (int nt = 0; nt < 8; ++nt) {
        const int col = nt * 16 + lr;
        bv[nt] = bias[col]; gv[nt] = g[col]; tv[nt] = bt[col];
    }

#pragma unroll
    for (int rt = 0; rt < 2; ++rt) {
        float s1[4] = {0.f, 0.f, 0.f, 0.f};
        float s2[4] = {0.f, 0.f, 0.f, 0.f};
#pragma unroll
        for (int nt = 0; nt < 8; ++nt)
#pragma unroll
            for (int j = 0; j < 4; ++j) {
                const float v = acc[rt][nt][j] + bv[nt];
                acc[rt][nt][j] = v;
                s1[j] += v;
                s2[j] += v * v;
            }
#pragma unroll
        for (int j = 0; j < 4; ++j)
#pragma unroll
            for (int o = 1; o < 16; o <<= 1) {
                s1[j] += __shfl_xor(s1[j], o);
                s2[j] += __shfl_xor(s2[j], o);
            }
#pragma unroll
        for (int j = 0; j < 4; ++j) {
            const int r = row0 + rt * 16 + kg * 4 + j;
            const float mu = s1[j] * (1.0f / 128.0f);
            const float var = s2[j] * (1.0f / 128.0f) - mu * mu;
            const float rs = rsqrtf(var + 1e-5f);
            if (r < NN) {
#pragma unroll
                for (int nt = 0; nt < 8; ++nt) {
                    const float y = fmaxf((acc[rt][nt][j] - mu) * rs * gv[nt] + tv[nt], 0.f);
                    const int col = nt * 16 + lr;
                    if constexpr (FP32OUT)
                        ((float*)outp)[(size_t)r * 128 + col] = y;
                    else
                        ((u16*)outp)[(size_t)r * 128 + col] = (u16)f2bf(y);
                }
            }
        }
    }
}

extern "C" void kernel_launch(void* const* d_in, const int* in_sizes, int n_in,
                              void* d_out, int out_size, void* d_ws, size_t ws_size,
                              hipStream_t stream) {
    const float* x   = (const float*)d_in[0];
    const int*   ei  = (const int*)d_in[1];
    const float* W1  = (const float*)d_in[2];
    const float* b1  = (const float*)d_in[3];
    const float* g1  = (const float*)d_in[4];
    const float* bt1 = (const float*)d_in[5];
    const float* W2  = (const float*)d_in[6];
    const float* b2  = (const float*)d_in[7];
    const float* g2  = (const float*)d_in[8];
    const float* bt2 = (const float*)d_in[9];

    const int* src = ei;
    const int* dst = ei + NE;

    // workspace layout (4B units)
    const int NP = (NN + 256 + 255) & ~255;       // covers NN+1
    int*   gcnt    = (int*)d_ws;                   // 256
    int*   bbase   = gcnt + 256;                   // 256 (197 used)
    int*   bfill   = bbase + 256;                  // 256
    int*   off     = bfill + 256;                  // NP
    float* dinv    = (float*)(off + NP);           // NP
    uint2* csr     = (uint2*)(dinv + NP);          // NE uint2 (12.8 MB)
    u32*   binned  = (u32*)(csr + NE);             // NE u32 (6.4 MB)
    int*   csr_tmp = (int*)(binned + NE);          // NE int (6.4 MB)
    u16*   aggx    = (u16*)binned;                 // NN*64 bf16, aliases binned+csr_tmp
    u16*   xb      = (u16*)(csr_tmp + NE);         // NN*64 bf16 (12.8 MB)
    u16*   aggh    = xb + (size_t)NN * 64;         // NN*128 bf16 (25.6 MB)
    u16*   WT1     = aggh + (size_t)NN * 128;      // 128*64 bf16
    u16*   WT2     = WT1 + 128 * 64;               // 128*128 bf16
    u16*   h1      = (u16*)d_out;                  // NN*128 bf16 in d_out (dead before final write)

    // ---- build CSR (shared by both layers) ----
    hipMemsetAsync(gcnt, 0, NBKT * sizeof(int), stream);
    kA1_count<<<ABLK, 256, 0, stream>>>(dst, gcnt);
    kA2_scan<<<1, 256, 0, stream>>>(gcnt, bbase, bfill, off);
    kA3_bin<<<ABLK, 256, 0, stream>>>(src, dst, bfill, binned);
    kB_fill<<<NBKT, 256, 0, stream>>>(binned, bbase, off, dinv, csr_tmp);
    k_wgt<<<(NE + 255) / 256, 256, 0, stream>>>(csr_tmp, dinv, csr);

    // ---- prep: x -> bf16, W -> transposed bf16 ----
    k_cvt<<<(NN * 8 + 255) / 256, 256, 0, stream>>>(x, xb);
    k_wt<<<(64 * 128 + 255) / 256, 256, 0, stream>>>(W1, WT1, 64);
    k_wt<<<(128 * 128 + 255) / 256, 256, 0, stream>>>(W2, WT2, 128);

    // ---- layer 1: agg(x) -> gemm+LN+ReLU -> h1 (bf16, in d_out) ----
    k_agg64<<<NN / 4, 256, 0, stream>>>(xb, off, csr, dinv, aggx);
    k_gemm_ln<64, false><<<(NN + 127) / 128, 256, 0, stream>>>(aggx, WT1, b1, g1, bt1, h1);

    // ---- layer 2: agg(h1) -> gemm+LN+ReLU -> out (fp32) ----
    k_agg128<<<NN / 4, 256, 0, stream>>>(h1, off, csr, dinv, aggh);
    k_gemm_ln<128, true><<<(NN + 127) / 128, 256, 0, stream>>>(aggh, WT2, b2, g2, bt2, d_out);
}

// Round 9
// 216.367 us; speedup vs baseline: 1.5724x; 1.1691x over previous
//
#include <hip/hip_runtime.h>

#define NN 100000
#define NE 1600000
#define NBKT 196                 // ceil(NN / 512)
#define CAP 12288                // per-bucket csr capacity (max ~8600 expected)
#define EPB 8192                 // edges per block in binning pass
#define ABLK ((NE + EPB - 1) / EPB)  // 196
typedef unsigned short u16;
typedef unsigned int u32;

typedef __attribute__((ext_vector_type(8))) short short8v;
typedef __attribute__((ext_vector_type(4))) float f32x4;

// ---- bf16 helpers (round-to-nearest-even) ----
__device__ __forceinline__ u32 f2bf(float f) {
    u32 u = __float_as_uint(f);
    return (u + 0x7fffu + ((u >> 16) & 1u)) >> 16;
}
__device__ __forceinline__ u32 pack2(float a, float b) {
    return f2bf(a) | (f2bf(b) << 16);
}
__device__ __forceinline__ void accum8(float* a, uint4 u, float w) {
    a[0] += __uint_as_float(u.x << 16) * w;
    a[1] += __uint_as_float(u.x & 0xffff0000u) * w;
    a[2] += __uint_as_float(u.y << 16) * w;
    a[3] += __uint_as_float(u.y & 0xffff0000u) * w;
    a[4] += __uint_as_float(u.z << 16) * w;
    a[5] += __uint_as_float(u.z & 0xffff0000u) * w;
    a[6] += __uint_as_float(u.w << 16) * w;
    a[7] += __uint_as_float(u.w & 0xffff0000u) * w;
}

// ---------------- bin edges into fixed-capacity buckets ---------------------
// binned[bkt*CAP + pos] = src<<9 | (dst&511); gcnt[bkt] = bucket count.
__global__ __launch_bounds__(256) void kA_bin(const int* __restrict__ src,
                                              const int* __restrict__ dst,
                                              int* __restrict__ gcnt,
                                              u32* __restrict__ binned) {
    __shared__ int bc[NBKT];
    __shared__ int cbase[NBKT];
    const int tid = threadIdx.x;
    for (int i = tid; i < NBKT; i += 256) bc[i] = 0;
    __syncthreads();
    const int e0 = blockIdx.x * EPB;
#pragma unroll
    for (int i = 0; i < EPB / 256; ++i) {
        const int e = e0 + i * 256 + tid;
        if (e < NE) atomicAdd(&bc[dst[e] >> 9], 1);
    }
    __syncthreads();
    for (int i = tid; i < NBKT; i += 256)
        cbase[i] = bc[i] ? atomicAdd(&gcnt[i], bc[i]) : 0;
    __syncthreads();
    for (int i = tid; i < NBKT; i += 256) bc[i] = 0;  // reuse as cursor
    __syncthreads();
#pragma unroll
    for (int i = 0; i < EPB / 256; ++i) {
        const int e = e0 + i * 256 + tid;
        if (e < NE) {
            const int d = dst[e];
            const int bkt = d >> 9;
            const int p = atomicAdd(&bc[bkt], 1);
            binned[bkt * CAP + cbase[bkt] + p] = ((u32)src[e] << 9) | (u32)(d & 511);
        }
    }
}

// ---------------- per-bucket: counts -> off2/dinv, fill csr (int src) -------
__global__ __launch_bounds__(256) void kB_fill(const u32* __restrict__ binned,
                                               const int* __restrict__ gcnt,
                                               int2* __restrict__ off2,
                                               float* __restrict__ dinv,
                                               int* __restrict__ csr) {
    __shared__ int lcnt[512];
    __shared__ int lpos[512];
    __shared__ int ws[4];
    const int b = blockIdx.x;
    const int tid = threadIdx.x;
    const int cnt = gcnt[b];
    const int base0 = b * CAP;
    const int node0 = b << 9;
    lcnt[tid] = 0;
    lcnt[tid + 256] = 0;
    __syncthreads();
    for (int e = tid; e < cnt; e += 256)
        atomicAdd(&lcnt[binned[base0 + e] & 511], 1);
    __syncthreads();
    const int c0 = lcnt[tid * 2], c1 = lcnt[tid * 2 + 1];
    const int s = c0 + c1;
    const int lane = tid & 63, w = tid >> 6;
    int incl = s;
#pragma unroll
    for (int o = 1; o < 64; o <<= 1) {
        const int u = __shfl_up(incl, o);
        if (lane >= o) incl += u;
    }
    if (lane == 63) ws[w] = incl;
    __syncthreads();
    int base = incl - s;
    for (int i = 0; i < w; ++i) base += ws[i];
    lpos[tid * 2] = base;
    lpos[tid * 2 + 1] = base + c0;
    const int n0 = node0 + tid * 2;
    if (n0 < NN) {
        off2[n0] = make_int2(base0 + base, base0 + base + c0);
        dinv[n0] = rsqrtf(1.0f + (float)c0);
    }
    if (n0 + 1 < NN) {
        off2[n0 + 1] = make_int2(base0 + base + c0, base0 + base + c0 + c1);
        dinv[n0 + 1] = rsqrtf(1.0f + (float)c1);
    }
    __syncthreads();
    for (int e = tid; e < cnt; e += 256) {
        const u32 u = binned[base0 + e];
        const int p = atomicAdd(&lpos[u & 511], 1);
        csr[base0 + p] = (int)(u >> 9);
    }
}

// ---------------- x fp32 -> bf16, pre-scaled by dinv[row] -------------------
__global__ __launch_bounds__(256) void k_cvt(const float* __restrict__ x,
                                             const float* __restrict__ dinv,
                                             u16* __restrict__ xb) {
    const int i = blockIdx.x * 256 + threadIdx.x;  // over NN*8
    if (i < NN * 8) {
        const int row = i >> 3;
        const float dr = dinv[row];
        const float4 v0 = *(const float4*)&x[(size_t)i * 8];
        const float4 v1 = *(const float4*)&x[(size_t)i * 8 + 4];
        uint4 o;
        o.x = pack2(v0.x * dr, v0.y * dr); o.y = pack2(v0.z * dr, v0.w * dr);
        o.z = pack2(v1.x * dr, v1.y * dr); o.w = pack2(v1.z * dr, v1.w * dr);
        *(uint4*)&xb[(size_t)i * 8] = o;
    }
}

// ---------------- W[K][128] fp32 -> WT[128][K] bf16 (transposed) ------------
__global__ __launch_bounds__(256) void k_wt(const float* __restrict__ W,
                                            u16* __restrict__ WT, int K) {
    const int i = blockIdx.x * 256 + threadIdx.x;
    if (i < K * 128) {
        const int k = i >> 7, c = i & 127;
        WT[c * K + k] = (u16)f2bf(W[i]);
    }
}

// ---------------- gather-sum of pre-scaled 64-col bf16 rows -----------------
// 8 sub-groups x 8 lanes; 16 rows in flight (2x unroll, csr prefetch).
__global__ __launch_bounds__(256) void k_agg64(const u16* __restrict__ A,
                                               const int2* __restrict__ off2,
                                               const int* __restrict__ csr,
                                               const float* __restrict__ dinv,
                                               u16* __restrict__ out) {
    const int node = blockIdx.x * 4 + (threadIdx.x >> 6);
    const int lane = threadIdx.x & 63;
    const int sub = lane >> 3, l = lane & 7;
    const u32 coff = (u32)l << 4;
    const char* Ab = (const char*)A;
    const float di = dinv[node];
    float a[8] = {};
    {
        const uint4 u = *(const uint4*)(Ab + (u32)node * 128u + coff);
        accum8(a, u, (sub == 0) ? 1.0f : 0.0f);
    }
    const int2 oe = off2[node];
    int base = oe.x;
    const int e1 = oe.y;
    u32 iA = 0, iB = 0;
    float vA = 0.f, vB = 0.f;
    if (base < e1) {
        const int eA = base + sub, eB = base + sub + 8;
        iA = (u32)csr[min(eA, e1 - 1)];
        iB = (u32)csr[min(eB, e1 - 1)];
        vA = (eA < e1) ? 1.f : 0.f;
        vB = (eB < e1) ? 1.f : 0.f;
    }
    while (base < e1) {
        const uint4 uA = *(const uint4*)(Ab + iA * 128u + coff);
        const uint4 uB = *(const uint4*)(Ab + iB * 128u + coff);
        const float wA = vA, wB = vB;
        base += 16;
        if (base < e1) {
            const int eA = base + sub, eB = base + sub + 8;
            iA = (u32)csr[min(eA, e1 - 1)];
            iB = (u32)csr[min(eB, e1 - 1)];
            vA = (eA < e1) ? 1.f : 0.f;
            vB = (eB < e1) ? 1.f : 0.f;
        }
        accum8(a, uA, wA);
        accum8(a, uB, wB);
    }
#pragma unroll
    for (int i = 0; i < 8; ++i) {
        a[i] += __shfl_xor(a[i], 8);
        a[i] += __shfl_xor(a[i], 16);
        a[i] += __shfl_xor(a[i], 32);
    }
    if (sub == 0) {
        uint4 o;
        o.x = pack2(a[0] * di, a[1] * di); o.y = pack2(a[2] * di, a[3] * di);
        o.z = pack2(a[4] * di, a[5] * di); o.w = pack2(a[6] * di, a[7] * di);
        *(uint4*)((char*)out + (u32)node * 128u + coff) = o;
    }
}

// ---------------- gather-sum of pre-scaled 128-col bf16 rows ----------------
// 4 sub-groups x 16 lanes; 8 rows in flight (2x unroll, csr prefetch).
__global__ __launch_bounds__(256) void k_agg128(const u16* __restrict__ A,
                                                const int2* __restrict__ off2,
                                                const int* __restrict__ csr,
                                                const float* __restrict__ dinv,
                                                u16* __restrict__ out) {
    const int node = blockIdx.x * 4 + (threadIdx.x >> 6);
    const int lane = threadIdx.x & 63;
    const int sub = lane >> 4, l = lane & 15;
    const u32 coff = (u32)l << 4;
    const char* Ab = (const char*)A;
    const float di = dinv[node];
    float a[8] = {};
    {
        const uint4 u = *(const uint4*)(Ab + ((u32)node << 8) + coff);
        accum8(a, u, (sub == 0) ? 1.0f : 0.0f);
    }
    const int2 oe = off2[node];
    int base = oe.x;
    const int e1 = oe.y;
    u32 iA = 0, iB = 0;
    float vA = 0.f, vB = 0.f;
    if (base < e1) {
        const int eA = base + sub, eB = base + sub + 4;
        iA = (u32)csr[min(eA, e1 - 1)];
        iB = (u32)csr[min(eB, e1 - 1)];
        vA = (eA < e1) ? 1.f : 0.f;
        vB = (eB < e1) ? 1.f : 0.f;
    }
    while (base < e1) {
        const uint4 uA = *(const uint4*)(Ab + (iA << 8) + coff);
        const uint4 uB = *(const uint4*)(Ab + (iB << 8) + coff);
        const float wA = vA, wB = vB;
        base += 8;
        if (base < e1) {
            const int eA = base + sub, eB = base + sub + 4;
            iA = (u32)csr[min(eA, e1 - 1)];
            iB = (u32)csr[min(eB, e1 - 1)];
            vA = (eA < e1) ? 1.f : 0.f;
            vB = (eB < e1) ? 1.f : 0.f;
        }
        accum8(a, uA, wA);
        accum8(a, uB, wB);
    }
#pragma unroll
    for (int i = 0; i < 8; ++i) {
        a[i] += __shfl_xor(a[i], 16);
        a[i] += __shfl_xor(a[i], 32);
    }
    if (sub == 0) {
        uint4 o;
        o.x = pack2(a[0] * di, a[1] * di); o.y = pack2(a[2] * di, a[3] * di);
        o.z = pack2(a[4] * di, a[5] * di); o.w = pack2(a[6] * di, a[7] * di);
        *(uint4*)((char*)out + ((u32)node << 8) + coff) = o;
    }
}

// ---------------- MFMA GEMM + bias + LayerNorm + ReLU (+optional prescale) --
// A[NN][K] bf16 @ WT[128][K] bf16 -> out [NN][128] (bf16 or fp32).
template<int K, bool FP32OUT, bool PRESCALE>
__global__ __launch_bounds__(256) void k_gemm_ln(const u16* __restrict__ Ain,
                                                 const u16* __restrict__ WT,
                                                 const float* __restrict__ bias,
                                                 const float* __restrict__ g,
                                                 const float* __restrict__ bt,
                                                 const float* __restrict__ dinv,
                                                 void* __restrict__ outp) {
    const int tid = threadIdx.x;
    const int wv = tid >> 6, lane = tid & 63;
    const int lr = lane & 15, kg = lane >> 4;
    const int row0 = blockIdx.x * 128 + wv * 32;

    short8v af[2][K / 32];
#pragma unroll
    for (int rt = 0; rt < 2; ++rt) {
        const int r = min(row0 + rt * 16 + lr, NN - 1);
#pragma unroll
        for (int kk = 0; kk < K / 32; ++kk)
            af[rt][kk] = *(const short8v*)&Ain[(size_t)r * K + kk * 32 + kg * 8];
    }
    f32x4 acc[2][8];
#pragma unroll
    for (int rt = 0; rt < 2; ++rt)
#pragma unroll
        for (int nt = 0; nt < 8; ++nt)
            acc[rt][nt] = (f32x4){0.f, 0.f, 0.f, 0.f};

#pragma unroll
    for (int nt = 0; nt < 8; ++nt) {
        const int col = nt * 16 + lr;
        short8v bf[K / 32];
#pragma unroll
        for (int kk = 0; kk < K / 32; ++kk)
            bf[kk] = *(const short8v*)&WT[col * K + kk * 32 + kg * 8];
#pragma unroll
        for (int rt = 0; rt < 2; ++rt)
#pragma unroll
            for (int kk = 0; kk < K / 32; ++kk)
                acc[rt][nt] = __builtin_amdgcn_mfma_f32_16x16x32_bf16(
                    af[rt][kk], bf[kk], acc[rt][nt], 0, 0, 0);
    }

    float bv[8], gv[8], tv[8];
#pragma unroll
    for (int nt = 0; nt < 8; ++nt) {
        const int col = nt * 16 + lr;
        bv[nt] = bias[col]; gv[nt] = g[col]; tv[nt] = bt[col];
    }

#pragma unroll
    for (int rt = 0; rt < 2; ++rt) {
        float s1[4] = {0.f, 0.f, 0.f, 0.f};
        float s2[4] = {0.f, 0.f, 0.f, 0.f};
#pragma unroll
        for (int nt = 0; nt < 8; ++nt)
#pragma unroll
            for (int j = 0; j < 4; ++j) {
                const float v = acc[rt][nt][j] + bv[nt];
                acc[rt][nt][j] = v;
                s1[j] += v;
                s2[j] += v * v;
            }
#pragma unroll
        for (int j = 0; j < 4; ++j)
#pragma unroll
            for (int o = 1; o < 16; o <<= 1) {
                s1[j] += __shfl_xor(s1[j], o);
                s2[j] += __shfl_xor(s2[j], o);
            }
#pragma unroll
        for (int j = 0; j < 4; ++j) {
            const int r = row0 + rt * 16 + kg * 4 + j;
            const float mu = s1[j] * (1.0f / 128.0f);
            const float var = s2[j] * (1.0f / 128.0f) - mu * mu;
            const float rs = rsqrtf(var + 1e-5f);
            if (r < NN) {
                const float dr = PRESCALE ? dinv[r] : 1.0f;
#pragma unroll
                for (int nt = 0; nt < 8; ++nt) {
                    const float y = fmaxf((acc[rt][nt][j] - mu) * rs * gv[nt] + tv[nt], 0.f) * dr;
                    const int col = nt * 16 + lr;
                    if constexpr (FP32OUT)
                        ((float*)outp)[(size_t)r * 128 + col] = y;
                    else
                        ((u16*)outp)[(size_t)r * 128 + col] = (u16)f2bf(y);
                }
            }
        }
    }
}

extern "C" void kernel_launch(void* const* d_in, const int* in_sizes, int n_in,
                              void* d_out, int out_size, void* d_ws, size_t ws_size,
                              hipStream_t stream) {
    const float* x   = (const float*)d_in[0];
    const int*   ei  = (const int*)d_in[1];
    const float* W1  = (const float*)d_in[2];
    const float* b1  = (const float*)d_in[3];
    const float* g1  = (const float*)d_in[4];
    const float* bt1 = (const float*)d_in[5];
    const float* W2  = (const float*)d_in[6];
    const float* b2  = (const float*)d_in[7];
    const float* g2  = (const float*)d_in[8];
    const float* bt2 = (const float*)d_in[9];

    const int* src = ei;
    const int* dst = ei + NE;

    // workspace layout (4B units)
    const int NP = (NN + 255) & ~255;
    int*   gcnt  = (int*)d_ws;                     // 256
    int2*  off2  = (int2*)(gcnt + 256);            // NN int2 (0.8 MB)
    float* dinv  = (float*)(off2 + NP);            // NP (0.4 MB)
    int*   csr   = (int*)(dinv + NP);              // NBKT*CAP ints (9.6 MB)
    u32*   binR  = (u32*)(csr + NBKT * CAP);       // 12.8 MB region: binned, then aggx
    u16*   xb    = (u16*)(binR + (size_t)NN * 32); // NN*64 bf16 (12.8 MB)
    u16*   aggh  = xb + (size_t)NN * 64;           // NN*128 bf16 (25.6 MB)
    u16*   WT1   = aggh + (size_t)NN * 128;        // 128*64 bf16
    u16*   WT2   = WT1 + 128 * 64;                 // 128*128 bf16
    u32*   binned = binR;                          // NBKT*CAP u32 (9.6 MB < 12.8)
    u16*   aggx  = (u16*)binR;                     // NN*64 bf16, after binned dead
    u16*   h1    = (u16*)d_out;                    // NN*128 bf16 in d_out

    // ---- build CSR (shared by both layers) ----
    hipMemsetAsync(gcnt, 0, NBKT * sizeof(int), stream);
    kA_bin<<<ABLK, 256, 0, stream>>>(src, dst, gcnt, binned);
    kB_fill<<<NBKT, 256, 0, stream>>>(binned, gcnt, off2, dinv, csr);

    // ---- prep ----
    k_cvt<<<(NN * 8 + 255) / 256, 256, 0, stream>>>(x, dinv, xb);
    k_wt<<<(64 * 128 + 255) / 256, 256, 0, stream>>>(W1, WT1, 64);
    k_wt<<<(128 * 128 + 255) / 256, 256, 0, stream>>>(W2, WT2, 128);

    // ---- layer 1: agg(x') -> gemm+LN+ReLU (+prescale) -> h1' (bf16, d_out) -
    k_agg64<<<NN / 4, 256, 0, stream>>>(xb, off2, csr, dinv, aggx);
    k_gemm_ln<64, false, true><<<(NN + 127) / 128, 256, 0, stream>>>(
        aggx, WT1, b1, g1, bt1, dinv, h1);

    // ---- layer 2: agg(h1') -> gemm+LN+ReLU -> out (fp32) ----
    k_agg128<<<NN / 4, 256, 0, stream>>>(h1, off2, csr, dinv, aggh);
    k_gemm_ln<128, true, false><<<(NN + 127) / 128, 256, 0, stream>>>(
        aggh, WT2, b2, g2, bt2, dinv, d_out);
}